// Round 2
// baseline (2060.975 us; speedup 1.0000x reference)
//
#include <hip/hip_runtime.h>
#include <hip/hip_bf16.h>
#include <cstdint>

// Problem constants: B=8, D=512, T=2048, K=8192. BT = 16384 queries.
constexpr int Dv = 512;
constexpr int Tv = 2048;
constexpr int Kv = 8192;
constexpr int BT = 16384;

constexpr int BQ = 128;   // queries per block tile
constexpr int BK = 128;   // codes per block tile
constexpr int BD = 32;    // d-chunk (32KB LDS total -> 4 blocks/CU)
constexpr int KSPL = 8;   // K split across blocks -> grid 1024 = 4 blocks/CU
constexpr int KPS = Kv / KSPL;   // 1024 codes per split

// ---------------------------------------------------------------- x_sq ----
__global__ void vq_xsq(const float* __restrict__ lat, float* __restrict__ xsq) {
    int q = blockIdx.x * 256 + threadIdx.x;      // 64 blocks x 256 = 16384
    int b = q >> 11, t = q & 2047;
    const float* p = lat + (size_t)b * Dv * Tv + t;
    float a = 0.f;
    #pragma unroll 8
    for (int d = 0; d < Dv; ++d) {
        float v = p[(size_t)d * Tv];
        a = fmaf(v, v, a);
    }
    xsq[q] = a;
}

// ---------------------------------------------------------------- e_sq ----
__global__ void vq_esq(const float* __restrict__ emb, float* __restrict__ esq) {
    int gid = blockIdx.x * 256 + threadIdx.x;
    int k = gid >> 6;                 // one wave per code row; 2048 blocks
    int l = threadIdx.x & 63;
    const float* p = emb + (size_t)k * Dv + l;
    float a = 0.f;
    #pragma unroll
    for (int i = 0; i < 8; ++i) {
        float v = p[i * 64];
        a = fmaf(v, v, a);
    }
    #pragma unroll
    for (int off = 32; off; off >>= 1) a += __shfl_down(a, off, 64);
    if (l == 0) esq[k] = a;
}

// ----------------------------------------------------------------- init ---
__global__ void vq_init(unsigned long long* __restrict__ keys) {
    int q = blockIdx.x * 256 + threadIdx.x;
    keys[q] = 0xFFFFFFFFFFFFFFFFull;
}

// ----------------------------------------------------------------- main ---
// grid 1024 = 128 q-blocks x 8 k-splits, 256 threads, 4 blocks/CU.
__global__ __launch_bounds__(256, 4) void vq_main(
        const float* __restrict__ lat, const float* __restrict__ emb,
        const float* __restrict__ xsq, const float* __restrict__ esq,
        unsigned long long* __restrict__ keys) {
    __shared__ float Xs[BD][BQ];        // 16 KB, linear [dd][q]
    __shared__ float Es[BD][BK];        // 16 KB, XOR-swizzled [dd][kk ^ ((dd>>2)<<2)]

    const int tid = threadIdx.x;
    const int bid = blockIdx.x;
    const int qb = bid & 127;
    const int ks = bid >> 7;
    const int q0 = qb * BQ;
    const int b  = q0 >> 11;
    const int t0 = q0 & 2047;
    const int k0base = ks * KPS;

    // lane remap: within a wave both tx and ty span 8 values -> all inner-loop
    // LDS b128 reads hit 8 distinct 16B lines = 2-way bank aliasing (free).
    const int tx = (tid & 7) | (((tid >> 6) & 1) << 3);        // [0,16) k dim
    const int ty = ((tid >> 3) & 7) | (((tid >> 7) & 1) << 3); // [0,16) q dim

    // staging maps
    const int sq   = tid & 31;   // X: 32 float4 lanes per 128-float row
    const int srow = tid >> 5;   // X: 8 row groups (dd = srow + i*8)
    const int dq   = tid & 7;    // E: d-quad 0..7 (dd = dq*4+c), coalesced global read
    const int ekk  = tid >> 3;   // E: kk = ekk + i*32
    const int fsw  = dq << 2;    // write-side XOR swizzle (bank spread: 2-way = free)

    float best[8];
    int   bidx[8];
    float xs[8];
    #pragma unroll
    for (int i = 0; i < 8; ++i) {
        best[i] = 3.4e38f;
        bidx[i] = 0x7fffffff;
        xs[i] = xsq[q0 + ty * 8 + i];
    }

    const float* latb = lat + (size_t)b * Dv * Tv + t0;
    float* const esw = &Es[0][0];

    for (int kc = 0; kc < KPS / BK; ++kc) {
        const int k0 = k0base + kc * BK;
        float c[8][8];
        #pragma unroll
        for (int i = 0; i < 8; ++i)
            #pragma unroll
            for (int j = 0; j < 8; ++j) c[i][j] = 0.f;

        for (int dc = 0; dc < Dv / BD; ++dc) {
            const int d0 = dc * BD;
            __syncthreads();
            // stage X tile: Xs[dd][q] = lat[b][d0+dd][t0+q]  (direct copy)
            #pragma unroll
            for (int i = 0; i < 4; ++i) {
                int dd = srow + i * 8;
                float4 v = *(const float4*)(latb + (size_t)(d0 + dd) * Tv + sq * 4);
                *(float4*)&Xs[dd][sq * 4] = v;
            }
            // stage E tile transposed + swizzled: elem (dd,kk) at word dd*128 + (kk^((dd>>2)<<2))
            #pragma unroll
            for (int i = 0; i < 4; ++i) {
                int kk = ekk + i * 32;
                float4 v = *(const float4*)(emb + (size_t)(k0 + kk) * Dv + d0 + dq * 4);
                int ksw = kk ^ fsw;
                esw[(dq * 4 + 0) * BK + ksw] = v.x;
                esw[(dq * 4 + 1) * BK + ksw] = v.y;
                esw[(dq * 4 + 2) * BK + ksw] = v.z;
                esw[(dq * 4 + 3) * BK + ksw] = v.w;
            }
            __syncthreads();

            // accumulate: STRICTLY sequential fp32 fma chain over d (matches
            // the np reference/BLAS accumulation rounding; same order as the
            // previously-passing kernel)
            #pragma unroll 4
            for (int dd = 0; dd < BD; ++dd) {
                const int g = (dd >> 2) << 2;   // read-side un-swizzle (compile-time)
                const float4 xa = *(const float4*)&Xs[dd][ty * 8];
                const float4 xb = *(const float4*)&Xs[dd][ty * 8 + 4];
                const float4 ea = *(const float4*)&esw[dd * BK + ((tx * 8) ^ g)];
                const float4 eb = *(const float4*)&esw[dd * BK + ((tx * 8 + 4) ^ g)];
                #define VQ_ROW(i, XV)                       \
                    c[i][0] = fmaf(XV, ea.x, c[i][0]);      \
                    c[i][1] = fmaf(XV, ea.y, c[i][1]);      \
                    c[i][2] = fmaf(XV, ea.z, c[i][2]);      \
                    c[i][3] = fmaf(XV, ea.w, c[i][3]);      \
                    c[i][4] = fmaf(XV, eb.x, c[i][4]);      \
                    c[i][5] = fmaf(XV, eb.y, c[i][5]);      \
                    c[i][6] = fmaf(XV, eb.z, c[i][6]);      \
                    c[i][7] = fmaf(XV, eb.w, c[i][7]);
                VQ_ROW(0, xa.x) VQ_ROW(1, xa.y) VQ_ROW(2, xa.z) VQ_ROW(3, xa.w)
                VQ_ROW(4, xb.x) VQ_ROW(5, xb.y) VQ_ROW(6, xb.z) VQ_ROW(7, xb.w)
                #undef VQ_ROW
            }
        }

        // distances + running argmin for this k-chunk.
        // dist = fl(fl(x_sq - 2c) + e_sq): fmaf(-2,c,xs) == x_sq - (2*c) exactly.
        float es8[8];
        #pragma unroll
        for (int j = 0; j < 8; ++j) es8[j] = esq[k0 + tx * 8 + j];
        #pragma unroll
        for (int i = 0; i < 8; ++i)
            #pragma unroll
            for (int j = 0; j < 8; ++j) {
                float dist = fmaf(-2.0f, c[i][j], xs[i]) + es8[j];
                int kk = k0 + tx * 8 + j;
                if (dist < best[i]) { best[i] = dist; bidx[i] = kk; }  // strict < : first index wins
            }
    }

    // cross-tx reduction via LDS (reuse tiles as scratch), then one atomicMin
    // per (q, split) on a packed sortable key: dist>0 -> fp32 bits monotone;
    // low 32 = index -> lexicographic (dist, idx) == np.argmin first-index rule.
    __syncthreads();
    float* redv = &Xs[0][0];         // 256*8 floats = 8 KB
    int*   redi = (int*)&Es[0][0];
    #pragma unroll
    for (int i = 0; i < 8; ++i) {
        redv[(ty * 16 + tx) * 8 + i] = best[i];
        redi[(ty * 16 + tx) * 8 + i] = bidx[i];
    }
    __syncthreads();
    if (tid < 128) {
        int yy = tid >> 3, ii = tid & 7;
        float bv = 3.4e38f;
        int bi = 0x7fffffff;
        #pragma unroll
        for (int t = 0; t < 16; ++t) {
            float v = redv[(yy * 16 + t) * 8 + ii];
            int  ix = redi[(yy * 16 + t) * 8 + ii];
            if (v < bv || (v == bv && ix < bi)) { bv = v; bi = ix; }
        }
        int q = q0 + yy * 8 + ii;
        unsigned long long key =
            ((unsigned long long)__float_as_uint(bv) << 32) | (unsigned int)bi;
        atomicMin(&keys[q], key);
    }
}

// --------------------------------------------------------------- gather ---
// out[b][d][t] = emb[idx[b*T+t]][d]; lanes along t -> coalesced stores.
__global__ void vq_gather(const float* __restrict__ emb,
                          const unsigned long long* __restrict__ keys,
                          float* __restrict__ out) {
    int blk = blockIdx.x;            // 256 blocks of 64 queries
    int tid = threadIdx.x;
    int tl = tid & 63, dg = tid >> 6;   // dg in [0,4)
    int q = blk * 64 + tl;
    int b = q >> 11, t = q & 2047;
    int idx = (int)(keys[q] & 0xFFFFFFFFull);
    const float* er = emb + (size_t)idx * Dv + dg * 128;
    float* ob = out + ((size_t)b * Dv + dg * 128) * Tv + t;
    #pragma unroll 8
    for (int i = 0; i < 128; ++i) ob[(size_t)i * Tv] = er[i];
}

// ---------------------------------------------------------------------------
extern "C" void kernel_launch(void* const* d_in, const int* in_sizes, int n_in,
                              void* d_out, int out_size, void* d_ws, size_t ws_size,
                              hipStream_t stream) {
    (void)in_sizes; (void)n_in; (void)out_size; (void)ws_size;
    const float* lat = (const float*)d_in[0];   // [8, 512, 2048]
    const float* emb = (const float*)d_in[1];   // [8192, 512]
    float* out = (float*)d_out;                 // [8, 512, 2048]

    char* ws = (char*)d_ws;
    float* xsq = (float*)(ws);                                   // 64 KB
    float* esq = (float*)(ws + (64 << 10));                      // 32 KB
    unsigned long long* keys =
        (unsigned long long*)(ws + (96 << 10));                  // 128 KB

    vq_init <<<BT / 256, 256, 0, stream>>>(keys);
    vq_xsq  <<<BT / 256, 256, 0, stream>>>(lat, xsq);
    vq_esq  <<<Kv / 4,   256, 0, stream>>>(emb, esq);
    vq_main <<<(BT / BQ) * KSPL, 256, 0, stream>>>(lat, emb, xsq, esq, keys);
    vq_gather<<<BT / 64, 256, 0, stream>>>(emb, keys, out);
}

// Round 3
// 1873.536 us; speedup vs baseline: 1.1000x; 1.1000x over previous
//
#include <hip/hip_runtime.h>
#include <hip/hip_bf16.h>
#include <cstdint>

// Problem constants: B=8, D=512, T=2048, K=8192. BT = 16384 queries.
constexpr int Dv = 512;
constexpr int Tv = 2048;
constexpr int Kv = 8192;
constexpr int BT = 16384;

constexpr int BQ = 128;   // queries per block tile
constexpr int BK = 128;   // codes per k-chunk
constexpr int BD = 32;    // d-chunk (32KB LDS total -> 3 blocks/CU easily)
constexpr int NKC = Kv / BK;   // 64 k-chunks total
constexpr int BPQ = 6;         // blocks per q-panel
constexpr int NBLK = (BT / BQ) * BPQ;  // 768 = 3 blocks/CU x 256 CU, zero tail

// ---------------------------------------------------------------- x_sq ----
__global__ void vq_xsq(const float* __restrict__ lat, float* __restrict__ xsq) {
    int q = blockIdx.x * 256 + threadIdx.x;      // 64 blocks x 256 = 16384
    int b = q >> 11, t = q & 2047;
    const float* p = lat + (size_t)b * Dv * Tv + t;
    float a = 0.f;
    #pragma unroll 8
    for (int d = 0; d < Dv; ++d) {
        float v = p[(size_t)d * Tv];
        a = fmaf(v, v, a);
    }
    xsq[q] = a;
}

// ---------------------------------------------------------------- e_sq ----
__global__ void vq_esq(const float* __restrict__ emb, float* __restrict__ esq) {
    int gid = blockIdx.x * 256 + threadIdx.x;
    int k = gid >> 6;                 // one wave per code row
    int l = threadIdx.x & 63;
    const float* p = emb + (size_t)k * Dv + l;
    float a = 0.f;
    #pragma unroll
    for (int i = 0; i < 8; ++i) {
        float v = p[i * 64];
        a = fmaf(v, v, a);
    }
    #pragma unroll
    for (int off = 32; off; off >>= 1) a += __shfl_down(a, off, 64);
    if (l == 0) esq[k] = a;
}

// ----------------------------------------------------------------- init ---
__global__ void vq_init(unsigned long long* __restrict__ keys) {
    int q = blockIdx.x * 256 + threadIdx.x;
    keys[q] = 0xFFFFFFFFFFFFFFFFull;
}

// ----------------------------------------------------------------- main ---
// grid 768 = 128 q-panels x 6 blocks; each block owns 10-11 contiguous
// k-chunks and keeps its argmin in registers across them.
// __launch_bounds__(256,3): 168-reg cap -> the ~112-VGPR no-spill allocation
// fits; 3 blocks/CU = 12 waves/CU.
__global__ __launch_bounds__(256, 3) void vq_main(
        const float* __restrict__ lat, const float* __restrict__ emb,
        const float* __restrict__ xsq, const float* __restrict__ esq,
        unsigned long long* __restrict__ keys) {
    __shared__ float Xs[BD][BQ];        // 16 KB, linear [dd][q]
    __shared__ float Es[BD][BK];        // 16 KB, XOR-swizzled [dd][kk ^ ((dd>>2)<<2)]

    const int tid = threadIdx.x;
    const int bid = blockIdx.x;
    const int qb  = bid / BPQ;
    const int sub = bid - qb * BPQ;
    const int q0 = qb * BQ;
    const int b  = q0 >> 11;
    const int t0 = q0 & 2047;
    // k-chunk range: 64 = 4*11 + 2*10
    const int cnt = (sub < 4) ? 11 : 10;
    const int kc0 = (sub < 4) ? sub * 11 : 44 + (sub - 4) * 10;

    // lane remap: within a wave both tx and ty span 8 values -> all inner-loop
    // LDS b128 reads hit 8 distinct 16B lines = 2-way bank aliasing (free).
    const int tx = (tid & 7) | (((tid >> 6) & 1) << 3);        // [0,16) k dim
    const int ty = ((tid >> 3) & 7) | (((tid >> 7) & 1) << 3); // [0,16) q dim

    // staging maps
    const int sq   = tid & 31;   // X: 32 float4 lanes per 128-float row
    const int srow = tid >> 5;   // X: 8 row groups (dd = srow + i*8)
    const int dq   = tid & 7;    // E: d-quad 0..7 (dd = dq*4+c), coalesced global read
    const int ekk  = tid >> 3;   // E: kk = ekk + i*32
    const int fsw  = dq << 2;    // write-side XOR swizzle (2-way = free)

    float best[8];
    int   bidx[8];
    float xs[8];
    #pragma unroll
    for (int i = 0; i < 8; ++i) {
        best[i] = 3.4e38f;
        bidx[i] = 0x7fffffff;
        xs[i] = xsq[q0 + ty * 8 + i];
    }

    const float* latb = lat + (size_t)b * Dv * Tv + t0;
    float* const esw = &Es[0][0];

    for (int kc = kc0; kc < kc0 + cnt; ++kc) {
        const int k0 = kc * BK;
        float c[8][8];
        #pragma unroll
        for (int i = 0; i < 8; ++i)
            #pragma unroll
            for (int j = 0; j < 8; ++j) c[i][j] = 0.f;

        for (int dc = 0; dc < Dv / BD; ++dc) {
            const int d0 = dc * BD;
            __syncthreads();
            // stage X tile: Xs[dd][q] = lat[b][d0+dd][t0+q]  (direct copy)
            #pragma unroll
            for (int i = 0; i < 4; ++i) {
                int dd = srow + i * 8;
                float4 v = *(const float4*)(latb + (size_t)(d0 + dd) * Tv + sq * 4);
                *(float4*)&Xs[dd][sq * 4] = v;
            }
            // stage E tile transposed + swizzled: (dd,kk) at word dd*128 + (kk^((dd>>2)<<2))
            #pragma unroll
            for (int i = 0; i < 4; ++i) {
                int kk = ekk + i * 32;
                float4 v = *(const float4*)(emb + (size_t)(k0 + kk) * Dv + d0 + dq * 4);
                int ksw = kk ^ fsw;
                esw[(dq * 4 + 0) * BK + ksw] = v.x;
                esw[(dq * 4 + 1) * BK + ksw] = v.y;
                esw[(dq * 4 + 2) * BK + ksw] = v.z;
                esw[(dq * 4 + 3) * BK + ksw] = v.w;
            }
            __syncthreads();

            // accumulate: STRICTLY sequential fp32 fma chain over d (matches
            // the np reference/BLAS accumulation rounding; identical chain to
            // the passing rounds 1-2 -> absmax stays 0)
            #pragma unroll 4
            for (int dd = 0; dd < BD; ++dd) {
                const int g = (dd >> 2) << 2;   // read-side un-swizzle
                const float4 xa = *(const float4*)&Xs[dd][ty * 8];
                const float4 xb = *(const float4*)&Xs[dd][ty * 8 + 4];
                const float4 ea = *(const float4*)&esw[dd * BK + ((tx * 8) ^ g)];
                const float4 eb = *(const float4*)&esw[dd * BK + ((tx * 8 + 4) ^ g)];
                #define VQ_ROW(i, XV)                       \
                    c[i][0] = fmaf(XV, ea.x, c[i][0]);      \
                    c[i][1] = fmaf(XV, ea.y, c[i][1]);      \
                    c[i][2] = fmaf(XV, ea.z, c[i][2]);      \
                    c[i][3] = fmaf(XV, ea.w, c[i][3]);      \
                    c[i][4] = fmaf(XV, eb.x, c[i][4]);      \
                    c[i][5] = fmaf(XV, eb.y, c[i][5]);      \
                    c[i][6] = fmaf(XV, eb.z, c[i][6]);      \
                    c[i][7] = fmaf(XV, eb.w, c[i][7]);
                VQ_ROW(0, xa.x) VQ_ROW(1, xa.y) VQ_ROW(2, xa.z) VQ_ROW(3, xa.w)
                VQ_ROW(4, xb.x) VQ_ROW(5, xb.y) VQ_ROW(6, xb.z) VQ_ROW(7, xb.w)
                #undef VQ_ROW
            }
        }

        // distances + running argmin for this k-chunk.
        // dist = fl(fl(x_sq - 2c) + e_sq): fmaf(-2,c,xs) == x_sq - (2*c) exactly.
        float es8[8];
        #pragma unroll
        for (int j = 0; j < 8; ++j) es8[j] = esq[k0 + tx * 8 + j];
        #pragma unroll
        for (int i = 0; i < 8; ++i)
            #pragma unroll
            for (int j = 0; j < 8; ++j) {
                float dist = fmaf(-2.0f, c[i][j], xs[i]) + es8[j];
                int kk = k0 + tx * 8 + j;
                if (dist < best[i]) { best[i] = dist; bidx[i] = kk; }  // strict < : first index wins
            }
    }

    // cross-tx reduction via LDS (reuse tiles as scratch), then one atomicMin
    // per q on a packed sortable key: dist>0 -> fp32 bits monotone;
    // low 32 = index -> lexicographic (dist, idx) == np.argmin first-index rule.
    __syncthreads();
    float* redv = &Xs[0][0];         // 256*8 floats = 8 KB
    int*   redi = (int*)&Es[0][0];
    #pragma unroll
    for (int i = 0; i < 8; ++i) {
        redv[(ty * 16 + tx) * 8 + i] = best[i];
        redi[(ty * 16 + tx) * 8 + i] = bidx[i];
    }
    __syncthreads();
    if (tid < 128) {
        int yy = tid >> 3, ii = tid & 7;
        float bv = 3.4e38f;
        int bi = 0x7fffffff;
        #pragma unroll
        for (int t = 0; t < 16; ++t) {
            float v = redv[(yy * 16 + t) * 8 + ii];
            int  ix = redi[(yy * 16 + t) * 8 + ii];
            if (v < bv || (v == bv && ix < bi)) { bv = v; bi = ix; }
        }
        int q = q0 + yy * 8 + ii;
        unsigned long long key =
            ((unsigned long long)__float_as_uint(bv) << 32) | (unsigned int)bi;
        atomicMin(&keys[q], key);
    }
}

// --------------------------------------------------------------- gather ---
// out[b][d][t] = emb[idx[b*T+t]][d]; lanes along t -> coalesced stores.
__global__ void vq_gather(const float* __restrict__ emb,
                          const unsigned long long* __restrict__ keys,
                          float* __restrict__ out) {
    int blk = blockIdx.x;            // 256 blocks of 64 queries
    int tid = threadIdx.x;
    int tl = tid & 63, dg = tid >> 6;   // dg in [0,4)
    int q = blk * 64 + tl;
    int b = q >> 11, t = q & 2047;
    int idx = (int)(keys[q] & 0xFFFFFFFFull);
    const float* er = emb + (size_t)idx * Dv + dg * 128;
    float* ob = out + ((size_t)b * Dv + dg * 128) * Tv + t;
    #pragma unroll 8
    for (int i = 0; i < 128; ++i) ob[(size_t)i * Tv] = er[i];
}

// ---------------------------------------------------------------------------
extern "C" void kernel_launch(void* const* d_in, const int* in_sizes, int n_in,
                              void* d_out, int out_size, void* d_ws, size_t ws_size,
                              hipStream_t stream) {
    (void)in_sizes; (void)n_in; (void)out_size; (void)ws_size;
    const float* lat = (const float*)d_in[0];   // [8, 512, 2048]
    const float* emb = (const float*)d_in[1];   // [8192, 512]
    float* out = (float*)d_out;                 // [8, 512, 2048]

    char* ws = (char*)d_ws;
    float* xsq = (float*)(ws);                                   // 64 KB
    float* esq = (float*)(ws + (64 << 10));                      // 32 KB
    unsigned long long* keys =
        (unsigned long long*)(ws + (96 << 10));                  // 128 KB

    vq_init <<<BT / 256, 256, 0, stream>>>(keys);
    vq_xsq  <<<BT / 256, 256, 0, stream>>>(lat, xsq);
    vq_esq  <<<Kv / 4,   256, 0, stream>>>(emb, esq);
    vq_main <<<NBLK, 256, 0, stream>>>(lat, emb, xsq, esq, keys);
    vq_gather<<<BT / 64, 256, 0, stream>>>(emb, keys, out);
}